// Round 5
// baseline (261.180 us; speedup 1.0000x reference)
//
#include <hip/hip_runtime.h>
#include <hip/hip_bf16.h>
#include <stdint.h>

using short4v = __attribute__((ext_vector_type(4))) short;
using short8  = __attribute__((ext_vector_type(8))) short;
using f32x4   = __attribute__((ext_vector_type(4))) float;

static constexpr int EMBED = 768;
static constexpr int NH    = 12;
static constexpr int HD    = 64;
static constexpr int BB    = 4;
static constexpr int NN    = 2048;
static constexpr int MROWS = BB * NN;          // 8192
static constexpr int QKV_COLS = 3 * EMBED;     // 2304
// Q prescale folds softmax scale AND log2(e) so P = exp2(S' - m')
static constexpr float QSCALE = 0.125f * 1.44269504088896340736f;

// round-to-nearest-even fp32 -> bf16 (bit path, used in cold kernels)
__device__ __forceinline__ short f2bs(float f) {
  unsigned int u = __float_as_uint(f);
  u += 0x7fffu + ((u >> 16) & 1u);
  return (short)(u >> 16);
}

// pack two fp32 -> two bf16 (RNE); compiler fuses to v_cvt_pk_bf16_f32
__device__ __forceinline__ unsigned int pk2(float lo, float hi) {
  __hip_bfloat162 h = __float22bfloat162_rn(float2{lo, hi});
  return *reinterpret_cast<unsigned int*>(&h);
}

// raw 2^x
__device__ __forceinline__ float exp2a(float x) {
  float r;
  asm("v_exp_f32 %0, %1" : "=v"(r) : "v"(x));
  return r;
}

__device__ __forceinline__ void gload_lds16(const void* g, void* l) {
  __builtin_amdgcn_global_load_lds(
      (const __attribute__((address_space(1))) unsigned int*)g,
      (__attribute__((address_space(3))) unsigned int*)l, 16, 0, 0);
}

// ---------------- fp32 -> bf16 bulk convert (x) ----------------
__global__ void k_cvt(const float* __restrict__ in, short* __restrict__ out, int n8) {
  int i = blockIdx.x * blockDim.x + threadIdx.x;
  if (i >= n8) return;
  const float4* p = reinterpret_cast<const float4*>(in) + (size_t)i * 2;
  float4 a = p[0], b = p[1];
  short8 o;
  o[0] = f2bs(a.x); o[1] = f2bs(a.y); o[2] = f2bs(a.z); o[3] = f2bs(a.w);
  o[4] = f2bs(b.x); o[5] = f2bs(b.y); o[6] = f2bs(b.z); o[7] = f2bs(b.w);
  reinterpret_cast<short8*>(out)[i] = o;
}

// ---------------- fp32 [K][NC] -> bf16 [NC][K] transpose ----------------
__global__ void k_transpose_cvt(const float* __restrict__ in, short* __restrict__ out,
                                int K, int NC) {
  __shared__ float t[32][33];
  int n0 = blockIdx.x * 32, k0 = blockIdx.y * 32;
  t[threadIdx.y][threadIdx.x] = in[(size_t)(k0 + threadIdx.y) * NC + n0 + threadIdx.x];
  __syncthreads();
  out[(size_t)(n0 + threadIdx.y) * K + k0 + threadIdx.x] = f2bs(t[threadIdx.x][threadIdx.y]);
}

// ---------------- bf16 GEMM, C = A[M][K] * Bt[N][K]^T + bias ----------------
template <int EPI>
__global__ __launch_bounds__(256)
void k_gemm_bt(const short* __restrict__ A, const short* __restrict__ Bt,
               const float* __restrict__ bias,
               short* __restrict__ q_out, short* __restrict__ k_out,
               short* __restrict__ vT_out, float* __restrict__ f_out,
               int M, int NC, int K) {
  __shared__ short sA[128][32];
  __shared__ short sB[128][32];
  int tid = threadIdx.x;
  int lane = tid & 63, wid = tid >> 6;
  int wr = wid >> 1, wc = wid & 1;
  int l15 = lane & 15, l4 = lane >> 4;
  int mtile = blockIdx.x * 128, ntile = blockIdx.y * 128;

  f32x4 acc[4][4];
#pragma unroll
  for (int i = 0; i < 4; ++i)
#pragma unroll
    for (int j = 0; j < 4; ++j) acc[i][j] = (f32x4){0.f, 0.f, 0.f, 0.f};

  const int rA = lane >> 2;
  const int cA = (lane & 3) * 8;

  for (int kk = 0; kk < K; kk += 32) {
    __syncthreads();
#pragma unroll
    for (int p = 0; p < 2; ++p) {
      int r0 = p * 64 + wid * 16;
      gload_lds16(A  + (size_t)(mtile + r0 + rA) * K + kk + cA, &sA[r0][0]);
      gload_lds16(Bt + (size_t)(ntile + r0 + rA) * K + kk + cA, &sB[r0][0]);
    }
    __syncthreads();
    short8 af[4], bfr[4];
#pragma unroll
    for (int i = 0; i < 4; ++i)
      af[i] = *reinterpret_cast<const short8*>(&sA[wr * 64 + i * 16 + l15][l4 * 8]);
#pragma unroll
    for (int j = 0; j < 4; ++j)
      bfr[j] = *reinterpret_cast<const short8*>(&sB[wc * 64 + j * 16 + l15][l4 * 8]);
#pragma unroll
    for (int i = 0; i < 4; ++i)
#pragma unroll
      for (int j = 0; j < 4; ++j)
        acc[i][j] = __builtin_amdgcn_mfma_f32_16x16x32_bf16(af[i], bfr[j], acc[i][j], 0, 0, 0);
  }

#pragma unroll
  for (int i = 0; i < 4; ++i) {
#pragma unroll
    for (int j = 0; j < 4; ++j) {
      int col = ntile + wc * 64 + j * 16 + l15;
      float bcol = bias[col];
      float vv[4];
#pragma unroll
      for (int r = 0; r < 4; ++r) vv[r] = acc[i][j][r] + bcol;
      if (EPI == 0) {
        int s = col / EMBED;
        int rem = col - s * EMBED;
        int hh = rem >> 6, d = rem & 63;
        int row0 = mtile + wr * 64 + i * 16 + l4 * 4;
        int b2 = row0 >> 11, n0 = row0 & 2047;
        if (s == 0) {
#pragma unroll
          for (int r = 0; r < 4; ++r)
            q_out[(size_t)((b2 * NH + hh) * NN + n0 + r) * HD + d] =
                f2bs(vv[r] * QSCALE);
        } else if (s == 1) {
#pragma unroll
          for (int r = 0; r < 4; ++r)
            k_out[(size_t)((b2 * NH + hh) * NN + n0 + r) * HD + d] = f2bs(vv[r]);
        } else {
          short4v o;
#pragma unroll
          for (int r = 0; r < 4; ++r) o[r] = f2bs(vv[r]);
          *reinterpret_cast<short4v*>(
              &vT_out[((size_t)(b2 * NH + hh) * HD + d) * NN + n0]) = o;
        }
      } else {
        int row0 = mtile + wr * 64 + i * 16 + l4 * 4;
#pragma unroll
        for (int r = 0; r < 4; ++r)
          f_out[(size_t)(row0 + r) * NC + col] = vv[r];
      }
    }
  }
}

// ---------------- flash attention (global-direct K/V frags, no barriers) ----
// grid 768 blocks (XCD-swizzled: 6 heads per XCD -> K/V L2-resident);
// 4 independent waves/block, 32 q-rows/wave, KVBLK=64.
// Only LDS use: per-wave P slab (bank-floor-optimal XOR layout).
__global__ __launch_bounds__(256)
void k_attn(const short* __restrict__ qb, const short* __restrict__ kb,
            const short* __restrict__ vtb, short* __restrict__ ob) {
  __shared__ __align__(16) short sP[4][32 * 64];  // 4KB per wave

  const int tid = threadIdx.x, lane = tid & 63, wid = tid >> 6;
  const int l15 = lane & 15, l4 = lane >> 4;

  // XCD-chunked swizzle: 768 blocks = 8 XCDs x 96 (6 heads x 16 q-tiles each)
  const int flat = blockIdx.x + (int)gridDim.x * blockIdx.y;
  const int swz  = (flat & 7) * 96 + (flat >> 3);
  const int bh   = swz >> 4, b = bh / NH, h = bh % NH;
  const int qr0  = (swz & 15) * 128 + wid * 32;

  const short* Q  = qb  + (size_t)bh * NN * HD;
  const short* Kp = kb  + (size_t)bh * NN * HD;
  const short* Vt = vtb + (size_t)bh * HD * NN;

  short8 qf[2][2];
#pragma unroll
  for (int mt = 0; mt < 2; ++mt)
#pragma unroll
    for (int c = 0; c < 2; ++c)
      qf[mt][c] = *reinterpret_cast<const short8*>(
          Q + (size_t)(qr0 + mt * 16 + l15) * HD + c * 32 + l4 * 8);

  f32x4 oT[2][4];
  float m_run[2], l_run[2];
#pragma unroll
  for (int mt = 0; mt < 2; ++mt) {
    m_run[mt] = -1e30f; l_run[mt] = 0.f;
#pragma unroll
    for (int dt = 0; dt < 4; ++dt) oT[mt][dt] = (f32x4){0.f, 0.f, 0.f, 0.f};
  }

  char* const pbase = (char*)&sP[wid][0];

#pragma unroll 1
  for (int t = 0; t < NN / 64; ++t) {
    const int kv0 = t * 64;

    // K fragments direct from L2: row kv0+nt*16+l15, 16B at c*32+l4*8
    short8 kf[2][4];
#pragma unroll
    for (int c = 0; c < 2; ++c)
#pragma unroll
      for (int nt = 0; nt < 4; ++nt)
        kf[c][nt] = *reinterpret_cast<const short8*>(
            Kp + (size_t)(kv0 + nt * 16 + l15) * HD + c * 32 + l4 * 8);
    // V^T fragments direct from L2: row d=dt*16+l15, 16B at kv0+c*32+l4*8
    short8 vf[2][4];
#pragma unroll
    for (int c = 0; c < 2; ++c)
#pragma unroll
      for (int dt = 0; dt < 4; ++dt)
        vf[c][dt] = *reinterpret_cast<const short8*>(
            Vt + (size_t)(dt * 16 + l15) * NN + kv0 + c * 32 + l4 * 8);

    // S^T = mfma(K rows, Q rows): sa[mt][nt][r] = S[q=mt*16+l15][kv=nt*16+l4*4+r]
    f32x4 sa[2][4];
#pragma unroll
    for (int mt = 0; mt < 2; ++mt)
#pragma unroll
      for (int nt = 0; nt < 4; ++nt) sa[mt][nt] = (f32x4){0.f, 0.f, 0.f, 0.f};
    __builtin_amdgcn_s_setprio(1);
#pragma unroll
    for (int c = 0; c < 2; ++c)
#pragma unroll
      for (int mt = 0; mt < 2; ++mt)
#pragma unroll
        for (int nt = 0; nt < 4; ++nt)
          sa[mt][nt] = __builtin_amdgcn_mfma_f32_16x16x32_bf16(
              kf[c][nt], qf[mt][c], sa[mt][nt], 0, 0, 0);
    __builtin_amdgcn_s_setprio(0);

    // online softmax in exp2 domain; defer-max (THR=8 -> P <= 256)
#pragma unroll
    for (int mt = 0; mt < 2; ++mt) {
      float mx = sa[mt][0][0];
#pragma unroll
      for (int nt = 0; nt < 4; ++nt)
#pragma unroll
        for (int r = 0; r < 4; ++r) mx = fmaxf(mx, sa[mt][nt][r]);
      mx = fmaxf(mx, __shfl_xor(mx, 16));
      mx = fmaxf(mx, __shfl_xor(mx, 32));
      if (!__all(mx <= m_run[mt] + 8.f)) {
        float mnew = fmaxf(m_run[mt], mx);
        float sc = exp2a(m_run[mt] - mnew);
        l_run[mt] *= sc;
        m_run[mt] = mnew;
#pragma unroll
        for (int dt = 0; dt < 4; ++dt) {
          oT[mt][dt][0] *= sc; oT[mt][dt][1] *= sc;
          oT[mt][dt][2] *= sc; oT[mt][dt][3] *= sc;
        }
      }
      float ps = 0.f;
#pragma unroll
      for (int nt = 0; nt < 4; ++nt)
#pragma unroll
        for (int r = 0; r < 4; ++r) {
          float p = exp2a(sa[mt][nt][r] - m_run[mt]);
          sa[mt][nt][r] = p;
          ps += p;
        }
      ps += __shfl_xor(ps, 16);
      ps += __shfl_xor(ps, 32);
      l_run[mt] += ps;

      // P -> sP, one b128 per (mt,c): chunk (c*4+l4)^(q&7), slots [g][nt1]
      int q = mt * 16 + l15;
#pragma unroll
      for (int c = 0; c < 2; ++c) {
        uint4 W;
        W.x = pk2(sa[mt][c * 2][0], sa[mt][c * 2][1]);
        W.y = pk2(sa[mt][c * 2][2], sa[mt][c * 2][3]);
        W.z = pk2(sa[mt][c * 2 + 1][0], sa[mt][c * 2 + 1][1]);
        W.w = pk2(sa[mt][c * 2 + 1][2], sa[mt][c * 2 + 1][3]);
        *reinterpret_cast<uint4*>(
            pbase + q * 128 + (((c * 4 + l4) ^ (q & 7)) << 4)) = W;
      }
    }

    // O^T += mfma(V^T rows, P): pf from sP (2x b64 per (mt,c), bank-floor)
#pragma unroll
    for (int c = 0; c < 2; ++c) {
      short8 pf[2];
#pragma unroll
      for (int mt = 0; mt < 2; ++mt) {
        int q = mt * 16 + l15;
        char* rb = pbase + q * 128 + ((l4 >> 1) * 8);
        int g0 = 2 * (l4 & 1);
        uint2 lo = *reinterpret_cast<uint2*>(rb + (((c * 4 + g0) ^ (q & 7)) << 4));
        uint2 hi = *reinterpret_cast<uint2*>(rb + (((c * 4 + g0 + 1) ^ (q & 7)) << 4));
        uint4 u;
        u.x = lo.x; u.y = lo.y; u.z = hi.x; u.w = hi.y;
        pf[mt] = *reinterpret_cast<short8*>(&u);
      }
      __builtin_amdgcn_s_setprio(1);
#pragma unroll
      for (int mt = 0; mt < 2; ++mt)
#pragma unroll
        for (int dt = 0; dt < 4; ++dt)
          oT[mt][dt] = __builtin_amdgcn_mfma_f32_16x16x32_bf16(
              vf[c][dt], pf[mt], oT[mt][dt], 0, 0, 0);
      __builtin_amdgcn_s_setprio(0);
    }
  }

  // epilogue: normalize, store O^T directly (8B stores)
#pragma unroll
  for (int mt = 0; mt < 2; ++mt) {
    float inv = 1.f / l_run[mt];
    int q = qr0 + mt * 16 + l15;
    short* orow = ob + (size_t)(b * NN + q) * EMBED + h * HD;
#pragma unroll
    for (int dt = 0; dt < 4; ++dt) {
      uint2 u;
      u.x = pk2(oT[mt][dt][0] * inv, oT[mt][dt][1] * inv);
      u.y = pk2(oT[mt][dt][2] * inv, oT[mt][dt][3] * inv);
      *reinterpret_cast<uint2*>(orow + dt * 16 + l4 * 4) = u;
    }
  }
}

extern "C" void kernel_launch(void* const* d_in, const int* in_sizes, int n_in,
                              void* d_out, int out_size, void* d_ws, size_t ws_size,
                              hipStream_t stream) {
  const float* x     = (const float*)d_in[0];
  const float* Wqkv  = (const float*)d_in[1];
  const float* bqkv  = (const float*)d_in[2];
  const float* Wproj = (const float*)d_in[3];
  const float* bproj = (const float*)d_in[4];
  float* out = (float*)d_out;

  char* ws = (char*)d_ws;
  const size_t SZ_X  = (size_t)MROWS * EMBED * 2;
  const size_t SZ_WQ = (size_t)QKV_COLS * EMBED * 2;
  const size_t SZ_WP = (size_t)EMBED * EMBED * 2;
  const size_t SZ_HB = (size_t)BB * NH * NN * HD * 2;
  if (ws_size < SZ_X * 2 + SZ_WQ + SZ_WP + SZ_HB * 3) return;

  short* xb     = (short*)ws;            ws += SZ_X;
  short* wqkvT  = (short*)ws;            ws += SZ_WQ;
  short* wprojT = (short*)ws;            ws += SZ_WP;
  short* qbuf   = (short*)ws;            ws += SZ_HB;
  short* kbuf   = (short*)ws;            ws += SZ_HB;
  short* vbufT  = (short*)ws;            ws += SZ_HB;   // [B,H,hd,N]
  short* aout   = (short*)ws;            ws += SZ_X;

  int n8 = MROWS * EMBED / 8;
  k_cvt<<<(n8 + 255) / 256, 256, 0, stream>>>(x, xb, n8);
  k_transpose_cvt<<<dim3(QKV_COLS / 32, EMBED / 32), dim3(32, 32), 0, stream>>>(
      Wqkv, wqkvT, EMBED, QKV_COLS);
  k_transpose_cvt<<<dim3(EMBED / 32, EMBED / 32), dim3(32, 32), 0, stream>>>(
      Wproj, wprojT, EMBED, EMBED);
  k_gemm_bt<0><<<dim3(MROWS / 128, QKV_COLS / 128), 256, 0, stream>>>(
      xb, wqkvT, bqkv, qbuf, kbuf, vbufT, nullptr, MROWS, QKV_COLS, EMBED);
  k_attn<<<dim3(NN / 128, BB * NH), 256, 0, stream>>>(qbuf, kbuf, vbufT, aout);
  k_gemm_bt<1><<<dim3(MROWS / 128, EMBED / 128), 256, 0, stream>>>(
      aout, wprojT, bproj, nullptr, nullptr, nullptr, out, MROWS, EMBED, EMBED);
}